// Round 7
// baseline (1370.711 us; speedup 1.0000x reference)
//
#include <hip/hip_runtime.h>

// PoissonPinn via 2nd-order forward-mode jet, hidden GEMMs on bf16 MFMA
// with hi/lo split-precision (3 MFMA terms: Ah*Bh + Ah*Bl + Al*Bh).
//
// Round-7 changes vs round-6:
//  * __launch_bounds__(256, 3): 3 blocks/CU (LDS 3x50688=152KB<=160KB;
//    regs 104 arch + 48 acc = 152 <= 170 budget without the A-dbuf, which
//    R6 proved neutral). The ~45% idle matrix time is epilogue/barrier
//    phases with no MFMA in flight; a 3rd independent block fills them.
//  * A-dbuf removed (R6: neutral; frees 24 VGPRs for the (256,3) budget).
//  * Boundary kernel fused into the eq grid (last 512 blocks) — removes
//    the ~50us serial tail; bnd blocks slot into the block pipeline.

constexpr int HID   = 256;
constexpr int MPTS  = 16;              // points per block (eq path)
constexpr int LDP   = HID + 8;         // padded LDS row stride (bf16 elems)
constexpr int WELEM = 3 * HID * HID;   // elems per split array in ws

typedef __bf16 bf16x8 __attribute__((ext_vector_type(8)));
typedef float  f32x4  __attribute__((ext_vector_type(4)));

__device__ __forceinline__ float fast_tanh(float x) {
    float e = __expf(2.0f * x);
    return 1.0f - 2.0f / (e + 1.0f);
}

// ---- prep: W1..W3 (fp32 [k][n]) -> bf16 hi/lo in fragment order ----
// Wf[l][n0][ks][lane][j]: lane=q*16+m reads W[k=ks*32+q*8+j][n=n0*16+m]
__global__ void prep_w(const float* __restrict__ W1,
                       const float* __restrict__ W2,
                       const float* __restrict__ W3,
                       __bf16* __restrict__ Wh, __bf16* __restrict__ Wl) {
    const int idx = blockIdx.x * 256 + threadIdx.x;   // 0 .. WELEM-1
    const int l   = idx >> 16;
    const int r   = idx & 0xFFFF;
    const int n0  = r >> 12;
    const int ks  = (r >> 9) & 7;
    const int ln  = (r >> 3) & 63;
    const int j   = r & 7;
    const int mm  = ln & 15;
    const int qq  = ln >> 4;
    const int k   = ks * 32 + qq * 8 + j;
    const int n   = n0 * 16 + mm;
    const float* W = (l == 0) ? W1 : (l == 1) ? W2 : W3;
    const float w  = W[k * HID + n];
    const __bf16 hi = (__bf16)w;
    Wh[idx] = hi;
    Wl[idx] = (__bf16)(w - (float)hi);
}

__global__ __launch_bounds__(256, 3)
void pinn_fused(const float* __restrict__ x,
                const float* __restrict__ xb,
                const float* __restrict__ W0, const float* __restrict__ b0,
                const float* __restrict__ W1f, const float* __restrict__ W2f,
                const float* __restrict__ W3f,
                const float* __restrict__ b1, const float* __restrict__ b2,
                const float* __restrict__ b3, const float* __restrict__ W4,
                const float* __restrict__ b4,
                const __bf16* __restrict__ Wh, const __bf16* __restrict__ Wl,
                int n_eq_blocks,
                float* __restrict__ out, float* __restrict__ out_b)
{
    __shared__ __align__(16) __bf16 Hh[3 * MPTS][LDP];
    __shared__ __align__(16) __bf16 Hl[3 * MPTS][LDP];

    const int tid  = threadIdx.x;
    const int lane = tid & 63;
    const int wv   = tid >> 6;

    if (blockIdx.x >= (unsigned)n_eq_blocks) {
        // ================= boundary path: plain fp32 forward =================
        float (*HV)[HID] = (float(*)[HID])&Hh[0][0];   // 16KB < 25KB of Hh
        const int rbase = wv * 4;
        const int pbase = (blockIdx.x - n_eq_blocks) * 16 + rbase;

        #pragma unroll
        for (int c = 0; c < 4; ++c) {
            const int   j  = lane + 64 * c;
            const float w  = W0[j];
            const float bb = b0[j];
            #pragma unroll
            for (int p = 0; p < 4; ++p)
                HV[rbase + p][j] = fast_tanh(xb[pbase + p] * w + bb);
        }
        __syncthreads();

        const float* Ws[3] = {W1f, W2f, W3f};
        const float* bs[3] = {b1, b2, b3};

        #pragma unroll
        for (int l = 0; l < 3; ++l) {
            const float* __restrict__ W = Ws[l];
            const float* __restrict__ b = bs[l];

            float zv[4][4];
            #pragma unroll
            for (int p = 0; p < 4; ++p)
                #pragma unroll
                for (int c = 0; c < 4; ++c)
                    zv[p][c] = b[lane + 64 * c];

            for (int i = 0; i < HID; i += 4) {
                float w[4][4];
                #pragma unroll
                for (int qq = 0; qq < 4; ++qq)
                    #pragma unroll
                    for (int c = 0; c < 4; ++c)
                        w[qq][c] = W[(i + qq) * HID + lane + 64 * c];

                #pragma unroll
                for (int p = 0; p < 4; ++p) {
                    const float4 av = *(const float4*)&HV[rbase + p][i];
                    #pragma unroll
                    for (int qq = 0; qq < 4; ++qq) {
                        const float a_v = ((const float*)&av)[qq];
                        #pragma unroll
                        for (int c = 0; c < 4; ++c)
                            zv[p][c] = fmaf(a_v, w[qq][c], zv[p][c]);
                    }
                }
            }
            __syncthreads();

            #pragma unroll
            for (int p = 0; p < 4; ++p)
                #pragma unroll
                for (int c = 0; c < 4; ++c)
                    HV[rbase + p][lane + 64 * c] = fast_tanh(zv[p][c]);
            __syncthreads();
        }

        const float bias4 = b4[0];
        #pragma unroll
        for (int p = 0; p < 4; ++p) {
            float acc = 0.0f;
            #pragma unroll
            for (int c = 0; c < 4; ++c) {
                const int j = lane + 64 * c;
                acc = fmaf(HV[rbase + p][j], W4[j], acc);
            }
            #pragma unroll
            for (int off = 32; off > 0; off >>= 1)
                acc += __shfl_down(acc, off, 64);
            if (lane == 0) out_b[pbase + p] = acc + bias4;
        }
        return;
    }

    // ==================== equation path: jet + MFMA ====================
    const int m  = lane & 15;     // A-frag row / C col
    const int q  = lane >> 4;     // quad
    const int pb = blockIdx.x * MPTS;

    bf16x8 AH[3], AL[3], BH0[4], BL0[4], BH1[4], BL1[4];
    f32x4  accv[4], accd[4], accs[4];

    auto loadB = [&](bf16x8* BH, bf16x8* BL,
                     const __bf16* whB, const __bf16* wlB, int ks) {
        #pragma unroll
        for (int nt = 0; nt < 4; ++nt) {
            const int off = ((wv * 4 + nt) * 8 + ks) * 512 + lane * 8;
            BH[nt] = *(const bf16x8*)(whB + off);
            BL[nt] = *(const bf16x8*)(wlB + off);
        }
    };
    auto loadA = [&](int ks) {
        const int kk = ks * 32 + q * 8;
        #pragma unroll
        for (int mt = 0; mt < 3; ++mt) {
            AH[mt] = *(const bf16x8*)&Hh[mt * MPTS + m][kk];
            AL[mt] = *(const bf16x8*)&Hl[mt * MPTS + m][kk];
        }
    };
    auto mfma36 = [&](bf16x8* BH, bf16x8* BL) {
        #pragma unroll
        for (int nt = 0; nt < 4; ++nt) {
            accv[nt] = __builtin_amdgcn_mfma_f32_16x16x32_bf16(AH[0], BH[nt], accv[nt], 0, 0, 0);
            accd[nt] = __builtin_amdgcn_mfma_f32_16x16x32_bf16(AH[1], BH[nt], accd[nt], 0, 0, 0);
            accs[nt] = __builtin_amdgcn_mfma_f32_16x16x32_bf16(AH[2], BH[nt], accs[nt], 0, 0, 0);
        }
        #pragma unroll
        for (int nt = 0; nt < 4; ++nt) {
            accv[nt] = __builtin_amdgcn_mfma_f32_16x16x32_bf16(AH[0], BL[nt], accv[nt], 0, 0, 0);
            accd[nt] = __builtin_amdgcn_mfma_f32_16x16x32_bf16(AH[1], BL[nt], accd[nt], 0, 0, 0);
            accs[nt] = __builtin_amdgcn_mfma_f32_16x16x32_bf16(AH[2], BL[nt], accs[nt], 0, 0, 0);
        }
        #pragma unroll
        for (int nt = 0; nt < 4; ++nt) {
            accv[nt] = __builtin_amdgcn_mfma_f32_16x16x32_bf16(AL[0], BH[nt], accv[nt], 0, 0, 0);
            accd[nt] = __builtin_amdgcn_mfma_f32_16x16x32_bf16(AL[1], BH[nt], accd[nt], 0, 0, 0);
            accs[nt] = __builtin_amdgcn_mfma_f32_16x16x32_bf16(AL[2], BH[nt], accs[nt], 0, 0, 0);
        }
    };

    // earliest possible: layer-1 ks=0 B-frags in flight during layer 0
    loadB(BH0, BL0, Wh, Wl, 0);

    // ---- layer 0: col c = tid, all 16 points ----
    {
        const int   c  = tid;
        const float w  = W0[c];
        const float bb = b0[c];
        #pragma unroll
        for (int p = 0; p < MPTS; ++p) {
            const float xv = x[pb + p];
            const float v  = fast_tanh(xv * w + bb);
            const float s2 = 1.0f - v * v;
            const float d  = s2 * w;
            const float s  = -2.0f * v * s2 * w * w;
            const __bf16 vh = (__bf16)v;  const __bf16 vl = (__bf16)(v - (float)vh);
            const __bf16 dh = (__bf16)d;  const __bf16 dl = (__bf16)(d - (float)dh);
            const __bf16 sh = (__bf16)s;  const __bf16 sl = (__bf16)(s - (float)sh);
            Hh[p][c]            = vh;  Hl[p][c]            = vl;
            Hh[MPTS + p][c]     = dh;  Hl[MPTS + p][c]     = dl;
            Hh[2 * MPTS + p][c] = sh;  Hl[2 * MPTS + p][c] = sl;
        }
    }
    __syncthreads();

    const float* bias[3] = {b1, b2, b3};

    for (int l = 0; l < 3; ++l) {
        const __bf16* __restrict__ whB = Wh + l * HID * HID;
        const __bf16* __restrict__ wlB = Wl + l * HID * HID;

        #pragma unroll
        for (int nt = 0; nt < 4; ++nt) {
            accv[nt] = (f32x4)0.0f;
            accd[nt] = (f32x4)0.0f;
            accs[nt] = (f32x4)0.0f;
        }

        loadA(0);
        #pragma unroll 1
        for (int ks = 0; ks < 8; ks += 2) {
            loadB(BH1, BL1, whB, wlB, ks + 1);       // prefetch odd step
            mfma36(BH0, BL0);
            loadA(ks + 1);
            if (ks + 2 < 8) loadB(BH0, BL0, whB, wlB, ks + 2);  // prefetch even
            mfma36(BH1, BL1);
            if (ks + 2 < 8) loadA(ks + 2);
        }

        // prefetch next layer's first B-frags; latency hides behind epilogue
        if (l < 2) loadB(BH0, BL0, whB + HID * HID, wlB + HID * HID, 0);

        // ---- jet epilogue (register-only), then LDS writeback ----
        const float* __restrict__ bvec = bias[l];
        float nv[4][4], nd[4][4], ns[4][4];
        #pragma unroll
        for (int nt = 0; nt < 4; ++nt) {
            const int col = (wv * 4 + nt) * 16 + m;
            const float bb = bvec[col];
            #pragma unroll
            for (int r = 0; r < 4; ++r) {
                const float zv = accv[nt][r] + bb;
                const float zd = accd[nt][r];
                const float zs = accs[nt][r];
                const float v  = fast_tanh(zv);
                const float s2 = 1.0f - v * v;
                nv[nt][r] = v;
                nd[nt][r] = s2 * zd;
                ns[nt][r] = s2 * zs - 2.0f * v * s2 * zd * zd;
            }
        }
        __syncthreads();   // all waves done READING H for this layer
        #pragma unroll
        for (int nt = 0; nt < 4; ++nt) {
            const int col = (wv * 4 + nt) * 16 + m;
            #pragma unroll
            for (int r = 0; r < 4; ++r) {
                const int pt = q * 4 + r;
                const float v = nv[nt][r], d = nd[nt][r], s = ns[nt][r];
                const __bf16 vh = (__bf16)v;  const __bf16 vl = (__bf16)(v - (float)vh);
                const __bf16 dh = (__bf16)d;  const __bf16 dl = (__bf16)(d - (float)dh);
                const __bf16 sh = (__bf16)s;  const __bf16 sl = (__bf16)(s - (float)sh);
                Hh[pt][col]            = vh;  Hl[pt][col]            = vl;
                Hh[MPTS + pt][col]     = dh;  Hl[MPTS + pt][col]     = dl;
                Hh[2 * MPTS + pt][col] = sh;  Hl[2 * MPTS + pt][col] = sl;
            }
        }
        __syncthreads();   // writes visible before next layer / final dot
    }

    // ---- final: d2u[pt] = sum_j h''[pt][j] * W4[j] ----
    {
        const int pt = tid >> 4;
        const int cc = tid & 15;
        float acc = 0.0f;
        #pragma unroll
        for (int j = 0; j < 16; ++j) {
            const int col = cc * 16 + j;
            const float hv = (float)Hh[2 * MPTS + pt][col] + (float)Hl[2 * MPTS + pt][col];
            acc = fmaf(hv, W4[col], acc);
        }
        #pragma unroll
        for (int off = 8; off > 0; off >>= 1)
            acc += __shfl_down(acc, off, 64);
        if (cc == 0) out[pb + pt] = acc;
    }
}

extern "C" void kernel_launch(void* const* d_in, const int* in_sizes, int n_in,
                              void* d_out, int out_size, void* d_ws, size_t ws_size,
                              hipStream_t stream) {
    const float* xe = (const float*)d_in[0];
    const float* xb = (const float*)d_in[1];
    const float* W0 = (const float*)d_in[2];
    const float* b0 = (const float*)d_in[3];
    const float* W1 = (const float*)d_in[4];
    const float* b1 = (const float*)d_in[5];
    const float* W2 = (const float*)d_in[6];
    const float* b2 = (const float*)d_in[7];
    const float* W3 = (const float*)d_in[8];
    const float* b3 = (const float*)d_in[9];
    const float* W4 = (const float*)d_in[10];
    const float* b4 = (const float*)d_in[11];
    float* out = (float*)d_out;

    const int n_eq = in_sizes[0];   // 262144
    const int n_b  = in_sizes[1];   // 8192

    __bf16* Wh = (__bf16*)d_ws;                    // 3*256*256 bf16 = 384 KB
    __bf16* Wl = Wh + WELEM;                       // another 384 KB

    prep_w<<<WELEM / 256, 256, 0, stream>>>(W1, W2, W3, Wh, Wl);

    const int nbe = n_eq / MPTS;       // 16384 eq blocks
    const int nbb = n_b / 16;          // 512 bnd blocks
    pinn_fused<<<nbe + nbb, 256, 0, stream>>>(
        xe, xb, W0, b0, W1, W2, W3, b1, b2, b3, W4, b4,
        Wh, Wl, nbe, out, out + n_eq);
}

// Round 8
// 1028.546 us; speedup vs baseline: 1.3327x; 1.3327x over previous
//
#include <hip/hip_runtime.h>

// PoissonPinn via 2nd-order forward-mode jet, hidden GEMMs on bf16 MFMA
// with hi/lo split-precision (3 MFMA terms: Ah*Bh + Ah*Bl + Al*Bh).
//
// Round-8 changes vs round-6/7:
//  * (256,3) is unreachable: compiler carves unified file into ~84 arch
//    VGPRs + AGPR chunk -> K-loop spill (R3, R7: 1.5GB WRITE_SIZE).
//    Instead get 4 waves/SIMD via 512-thread blocks: 8 waves/block, each
//    wave owns 2 n-tiles (was 4). LDS/block unchanged (50.7KB) -> 2
//    blocks/CU = 16 waves/CU. Per-wave regs: acc 24 + B-dbuf 32 + A 24 +
//    misc ~ 110 <= 128 budget @ __launch_bounds__(512,4). Per-wave
//    epilogue halves; each SIMD hosts waves of 2 unsynced blocks to cover
//    barrier/epilogue phases (R6 model: MFMA demand 11.2k cyc vs 20k wall).
//  * Boundary path fused (last 256 blocks, 32 pts/block).

constexpr int HID   = 256;
constexpr int MPTS  = 16;              // points per block (eq path)
constexpr int LDP   = HID + 8;         // padded LDS row stride (bf16 elems)
constexpr int WELEM = 3 * HID * HID;   // elems per split array in ws

typedef __bf16 bf16x8 __attribute__((ext_vector_type(8)));
typedef float  f32x4  __attribute__((ext_vector_type(4)));

__device__ __forceinline__ float fast_tanh(float x) {
    float e = __expf(2.0f * x);
    return 1.0f - 2.0f / (e + 1.0f);
}

// ---- prep: W1..W3 (fp32 [k][n]) -> bf16 hi/lo in fragment order ----
// Wf[l][n0][ks][lane][j]: lane=q*16+m reads W[k=ks*32+q*8+j][n=n0*16+m]
__global__ void prep_w(const float* __restrict__ W1,
                       const float* __restrict__ W2,
                       const float* __restrict__ W3,
                       __bf16* __restrict__ Wh, __bf16* __restrict__ Wl) {
    const int idx = blockIdx.x * 256 + threadIdx.x;   // 0 .. WELEM-1
    const int l   = idx >> 16;
    const int r   = idx & 0xFFFF;
    const int n0  = r >> 12;
    const int ks  = (r >> 9) & 7;
    const int ln  = (r >> 3) & 63;
    const int j   = r & 7;
    const int mm  = ln & 15;
    const int qq  = ln >> 4;
    const int k   = ks * 32 + qq * 8 + j;
    const int n   = n0 * 16 + mm;
    const float* W = (l == 0) ? W1 : (l == 1) ? W2 : W3;
    const float w  = W[k * HID + n];
    const __bf16 hi = (__bf16)w;
    Wh[idx] = hi;
    Wl[idx] = (__bf16)(w - (float)hi);
}

__global__ __launch_bounds__(512, 4)
void pinn_fused(const float* __restrict__ x,
                const float* __restrict__ xb,
                const float* __restrict__ W0, const float* __restrict__ b0,
                const float* __restrict__ W1f, const float* __restrict__ W2f,
                const float* __restrict__ W3f,
                const float* __restrict__ b1, const float* __restrict__ b2,
                const float* __restrict__ b3, const float* __restrict__ W4,
                const float* __restrict__ b4,
                const __bf16* __restrict__ Wh, const __bf16* __restrict__ Wl,
                int n_eq_blocks,
                float* __restrict__ out, float* __restrict__ out_b)
{
    // Hbuf[0] = hi, Hbuf[1] = lo; 2*48*264*2B = 50688 B
    __shared__ __align__(16) __bf16 Hbuf[2][3 * MPTS][LDP];
    auto Hh = Hbuf[0];
    auto Hl = Hbuf[1];

    const int tid  = threadIdx.x;
    const int lane = tid & 63;
    const int wv   = tid >> 6;      // 0..7

    if (blockIdx.x >= (unsigned)n_eq_blocks) {
        // ============ boundary path: plain fp32 forward, 32 pts ============
        float (*HV)[HID] = (float(*)[HID])&Hbuf[0][0][0];   // 32 KB < 50.7 KB
        const int rbase = wv * 4;
        const int pbase = (blockIdx.x - n_eq_blocks) * 32 + rbase;

        #pragma unroll
        for (int c = 0; c < 4; ++c) {
            const int   j  = lane + 64 * c;
            const float w  = W0[j];
            const float bb = b0[j];
            #pragma unroll
            for (int p = 0; p < 4; ++p)
                HV[rbase + p][j] = fast_tanh(xb[pbase + p] * w + bb);
        }
        __syncthreads();

        const float* Ws[3] = {W1f, W2f, W3f};
        const float* bs[3] = {b1, b2, b3};

        #pragma unroll
        for (int l = 0; l < 3; ++l) {
            const float* __restrict__ W = Ws[l];
            const float* __restrict__ b = bs[l];

            float zv[4][4];
            #pragma unroll
            for (int p = 0; p < 4; ++p)
                #pragma unroll
                for (int c = 0; c < 4; ++c)
                    zv[p][c] = b[lane + 64 * c];

            for (int i = 0; i < HID; i += 4) {
                float w[4][4];
                #pragma unroll
                for (int qq = 0; qq < 4; ++qq)
                    #pragma unroll
                    for (int c = 0; c < 4; ++c)
                        w[qq][c] = W[(i + qq) * HID + lane + 64 * c];

                #pragma unroll
                for (int p = 0; p < 4; ++p) {
                    const float4 av = *(const float4*)&HV[rbase + p][i];
                    #pragma unroll
                    for (int qq = 0; qq < 4; ++qq) {
                        const float a_v = ((const float*)&av)[qq];
                        #pragma unroll
                        for (int c = 0; c < 4; ++c)
                            zv[p][c] = fmaf(a_v, w[qq][c], zv[p][c]);
                    }
                }
            }
            __syncthreads();

            #pragma unroll
            for (int p = 0; p < 4; ++p)
                #pragma unroll
                for (int c = 0; c < 4; ++c)
                    HV[rbase + p][lane + 64 * c] = fast_tanh(zv[p][c]);
            __syncthreads();
        }

        const float bias4 = b4[0];
        #pragma unroll
        for (int p = 0; p < 4; ++p) {
            float acc = 0.0f;
            #pragma unroll
            for (int c = 0; c < 4; ++c) {
                const int j = lane + 64 * c;
                acc = fmaf(HV[rbase + p][j], W4[j], acc);
            }
            #pragma unroll
            for (int off = 32; off > 0; off >>= 1)
                acc += __shfl_down(acc, off, 64);
            if (lane == 0) out_b[pbase + p] = acc + bias4;
        }
        return;
    }

    // ==================== equation path: jet + MFMA ====================
    const int m  = lane & 15;     // A-frag row / C col
    const int q  = lane >> 4;     // quad
    const int pb = blockIdx.x * MPTS;

    bf16x8 AH[3], AL[3], BH0[2], BL0[2], BH1[2], BL1[2];
    f32x4  accv[2], accd[2], accs[2];

    auto loadB = [&](bf16x8* BH, bf16x8* BL,
                     const __bf16* whB, const __bf16* wlB, int ks) {
        #pragma unroll
        for (int nt = 0; nt < 2; ++nt) {
            const int off = ((wv * 2 + nt) * 8 + ks) * 512 + lane * 8;
            BH[nt] = *(const bf16x8*)(whB + off);
            BL[nt] = *(const bf16x8*)(wlB + off);
        }
    };
    auto loadA = [&](int ks) {
        const int kk = ks * 32 + q * 8;
        #pragma unroll
        for (int mt = 0; mt < 3; ++mt) {
            AH[mt] = *(const bf16x8*)&Hh[mt * MPTS + m][kk];
            AL[mt] = *(const bf16x8*)&Hl[mt * MPTS + m][kk];
        }
    };
    auto mfma18 = [&](bf16x8* BH, bf16x8* BL) {
        #pragma unroll
        for (int nt = 0; nt < 2; ++nt) {
            accv[nt] = __builtin_amdgcn_mfma_f32_16x16x32_bf16(AH[0], BH[nt], accv[nt], 0, 0, 0);
            accd[nt] = __builtin_amdgcn_mfma_f32_16x16x32_bf16(AH[1], BH[nt], accd[nt], 0, 0, 0);
            accs[nt] = __builtin_amdgcn_mfma_f32_16x16x32_bf16(AH[2], BH[nt], accs[nt], 0, 0, 0);
        }
        #pragma unroll
        for (int nt = 0; nt < 2; ++nt) {
            accv[nt] = __builtin_amdgcn_mfma_f32_16x16x32_bf16(AH[0], BL[nt], accv[nt], 0, 0, 0);
            accd[nt] = __builtin_amdgcn_mfma_f32_16x16x32_bf16(AH[1], BL[nt], accd[nt], 0, 0, 0);
            accs[nt] = __builtin_amdgcn_mfma_f32_16x16x32_bf16(AH[2], BL[nt], accs[nt], 0, 0, 0);
        }
        #pragma unroll
        for (int nt = 0; nt < 2; ++nt) {
            accv[nt] = __builtin_amdgcn_mfma_f32_16x16x32_bf16(AL[0], BH[nt], accv[nt], 0, 0, 0);
            accd[nt] = __builtin_amdgcn_mfma_f32_16x16x32_bf16(AL[1], BH[nt], accd[nt], 0, 0, 0);
            accs[nt] = __builtin_amdgcn_mfma_f32_16x16x32_bf16(AL[2], BH[nt], accs[nt], 0, 0, 0);
        }
    };

    // earliest possible: layer-1 ks=0 B-frags in flight during layer 0
    loadB(BH0, BL0, Wh, Wl, 0);

    // ---- layer 0: col c = tid&255, point-half gg = tid>>8 ----
    {
        const int   c  = tid & 255;
        const int   gg = tid >> 8;          // 0/1 -> points gg*8 .. gg*8+7
        const float w  = W0[c];
        const float bb = b0[c];
        #pragma unroll
        for (int p = 0; p < 8; ++p) {
            const int   pt = gg * 8 + p;
            const float xv = x[pb + pt];
            const float v  = fast_tanh(xv * w + bb);
            const float s2 = 1.0f - v * v;
            const float d  = s2 * w;
            const float s  = -2.0f * v * s2 * w * w;
            const __bf16 vh = (__bf16)v;  const __bf16 vl = (__bf16)(v - (float)vh);
            const __bf16 dh = (__bf16)d;  const __bf16 dl = (__bf16)(d - (float)dh);
            const __bf16 sh = (__bf16)s;  const __bf16 sl = (__bf16)(s - (float)sh);
            Hh[pt][c]            = vh;  Hl[pt][c]            = vl;
            Hh[MPTS + pt][c]     = dh;  Hl[MPTS + pt][c]     = dl;
            Hh[2 * MPTS + pt][c] = sh;  Hl[2 * MPTS + pt][c] = sl;
        }
    }
    __syncthreads();

    const float* bias[3] = {b1, b2, b3};

    for (int l = 0; l < 3; ++l) {
        const __bf16* __restrict__ whB = Wh + l * HID * HID;
        const __bf16* __restrict__ wlB = Wl + l * HID * HID;

        #pragma unroll
        for (int nt = 0; nt < 2; ++nt) {
            accv[nt] = (f32x4)0.0f;
            accd[nt] = (f32x4)0.0f;
            accs[nt] = (f32x4)0.0f;
        }

        loadA(0);
        #pragma unroll 1
        for (int ks = 0; ks < 8; ks += 2) {
            loadB(BH1, BL1, whB, wlB, ks + 1);       // prefetch odd step
            mfma18(BH0, BL0);
            loadA(ks + 1);
            if (ks + 2 < 8) loadB(BH0, BL0, whB, wlB, ks + 2);  // prefetch even
            mfma18(BH1, BL1);
            if (ks + 2 < 8) loadA(ks + 2);
        }

        // prefetch next layer's first B-frags; latency hides behind epilogue
        if (l < 2) loadB(BH0, BL0, whB + HID * HID, wlB + HID * HID, 0);

        // ---- jet epilogue (register-only), then LDS writeback ----
        const float* __restrict__ bvec = bias[l];
        float nv[2][4], nd[2][4], ns[2][4];
        #pragma unroll
        for (int nt = 0; nt < 2; ++nt) {
            const int col = (wv * 2 + nt) * 16 + m;
            const float bb = bvec[col];
            #pragma unroll
            for (int r = 0; r < 4; ++r) {
                const float zv = accv[nt][r] + bb;
                const float zd = accd[nt][r];
                const float zs = accs[nt][r];
                const float v  = fast_tanh(zv);
                const float s2 = 1.0f - v * v;
                nv[nt][r] = v;
                nd[nt][r] = s2 * zd;
                ns[nt][r] = s2 * zs - 2.0f * v * s2 * zd * zd;
            }
        }
        __syncthreads();   // all waves done READING H for this layer
        #pragma unroll
        for (int nt = 0; nt < 2; ++nt) {
            const int col = (wv * 2 + nt) * 16 + m;
            #pragma unroll
            for (int r = 0; r < 4; ++r) {
                const int pt = q * 4 + r;
                const float v = nv[nt][r], d = nd[nt][r], s = ns[nt][r];
                const __bf16 vh = (__bf16)v;  const __bf16 vl = (__bf16)(v - (float)vh);
                const __bf16 dh = (__bf16)d;  const __bf16 dl = (__bf16)(d - (float)dh);
                const __bf16 sh = (__bf16)s;  const __bf16 sl = (__bf16)(s - (float)sh);
                Hh[pt][col]            = vh;  Hl[pt][col]            = vl;
                Hh[MPTS + pt][col]     = dh;  Hl[MPTS + pt][col]     = dl;
                Hh[2 * MPTS + pt][col] = sh;  Hl[2 * MPTS + pt][col] = sl;
            }
        }
        __syncthreads();   // writes visible before next layer / final dot
    }

    // ---- final: d2u[pt] = sum_j h''[pt][j] * W4[j] ----
    {
        const int pt = tid >> 5;            // 0..15
        const int cc = tid & 31;            // 8 cols each
        const int row = 2 * MPTS + pt;
        const bf16x8 hh = *(const bf16x8*)&Hh[row][cc * 8];
        const bf16x8 hl = *(const bf16x8*)&Hl[row][cc * 8];
        float acc = 0.0f;
        #pragma unroll
        for (int j = 0; j < 8; ++j) {
            const float hv = (float)hh[j] + (float)hl[j];
            acc = fmaf(hv, W4[cc * 8 + j], acc);
        }
        #pragma unroll
        for (int off = 16; off > 0; off >>= 1)
            acc += __shfl_down(acc, off, 32);
        if (cc == 0) out[pb + pt] = acc;
    }
}

extern "C" void kernel_launch(void* const* d_in, const int* in_sizes, int n_in,
                              void* d_out, int out_size, void* d_ws, size_t ws_size,
                              hipStream_t stream) {
    const float* xe = (const float*)d_in[0];
    const float* xb = (const float*)d_in[1];
    const float* W0 = (const float*)d_in[2];
    const float* b0 = (const float*)d_in[3];
    const float* W1 = (const float*)d_in[4];
    const float* b1 = (const float*)d_in[5];
    const float* W2 = (const float*)d_in[6];
    const float* b2 = (const float*)d_in[7];
    const float* W3 = (const float*)d_in[8];
    const float* b3 = (const float*)d_in[9];
    const float* W4 = (const float*)d_in[10];
    const float* b4 = (const float*)d_in[11];
    float* out = (float*)d_out;

    const int n_eq = in_sizes[0];   // 262144
    const int n_b  = in_sizes[1];   // 8192

    __bf16* Wh = (__bf16*)d_ws;                    // 3*256*256 bf16 = 384 KB
    __bf16* Wl = Wh + WELEM;                       // another 384 KB

    prep_w<<<WELEM / 256, 256, 0, stream>>>(W1, W2, W3, Wh, Wl);

    const int nbe = n_eq / MPTS;       // 16384 eq blocks
    const int nbb = n_b / 32;          // 256 bnd blocks
    pinn_fused<<<nbe + nbb, 512, 0, stream>>>(
        xe, xb, W0, b0, W1, W2, W3, b1, b2, b3, W4, b4,
        Wh, Wl, nbe, out, out + n_eq);
}

// Round 9
// 986.841 us; speedup vs baseline: 1.3890x; 1.0423x over previous
//
#include <hip/hip_runtime.h>

// PoissonPinn via 2nd-order forward-mode jet, hidden GEMMs on bf16 MFMA
// with hi/lo split-precision (3 MFMA terms: Ah*Bh + Ah*Bl + Al*Bh).
//
// Round-9: 3 independent blocks/CU (256 thr, __launch_bounds__(256,3)).
// Evidence R5/R6/R8: MfmaUtil tracks independently-phased blocks per CU and
// per-wave burst length, not waves/SIMD. (256,3) caps arch VGPRs at ~84
// (R3/R7 spilled) -> shrink the live set to fit:
//  * B and A single-buffered (no dbuf, no next-layer prefetch): 32+24 regs.
//    Latency hiding via TLP: 3 waves/SIMD from 3 unsynced blocks.
//  * Epilogue fused: barrier -> compute+write straight from acc -> barrier
//    (kills the 48-float nv/nd/ns staging arrays that spilled R7).
//  * 36-MFMA bursts kept (4 n-tiles/wave). Spill tripwire: WRITE_SIZE ~1MB.

constexpr int HID   = 256;
constexpr int MPTS  = 16;              // points per block (eq path)
constexpr int LDP   = HID + 8;         // padded LDS row stride (bf16 elems)
constexpr int WELEM = 3 * HID * HID;   // elems per split array in ws

typedef __bf16 bf16x8 __attribute__((ext_vector_type(8)));
typedef float  f32x4  __attribute__((ext_vector_type(4)));

__device__ __forceinline__ float fast_tanh(float x) {
    float e = __expf(2.0f * x);
    return 1.0f - 2.0f / (e + 1.0f);
}

// ---- prep: W1..W3 (fp32 [k][n]) -> bf16 hi/lo in fragment order ----
// Wf[l][n0][ks][lane][j]: lane=q*16+m reads W[k=ks*32+q*8+j][n=n0*16+m]
__global__ void prep_w(const float* __restrict__ W1,
                       const float* __restrict__ W2,
                       const float* __restrict__ W3,
                       __bf16* __restrict__ Wh, __bf16* __restrict__ Wl) {
    const int idx = blockIdx.x * 256 + threadIdx.x;   // 0 .. WELEM-1
    const int l   = idx >> 16;
    const int r   = idx & 0xFFFF;
    const int n0  = r >> 12;
    const int ks  = (r >> 9) & 7;
    const int ln  = (r >> 3) & 63;
    const int j   = r & 7;
    const int mm  = ln & 15;
    const int qq  = ln >> 4;
    const int k   = ks * 32 + qq * 8 + j;
    const int n   = n0 * 16 + mm;
    const float* W = (l == 0) ? W1 : (l == 1) ? W2 : W3;
    const float w  = W[k * HID + n];
    const __bf16 hi = (__bf16)w;
    Wh[idx] = hi;
    Wl[idx] = (__bf16)(w - (float)hi);
}

__global__ __launch_bounds__(256, 3)
void pinn_fused(const float* __restrict__ x,
                const float* __restrict__ xb,
                const float* __restrict__ W0, const float* __restrict__ b0,
                const float* __restrict__ W1f, const float* __restrict__ W2f,
                const float* __restrict__ W3f,
                const float* __restrict__ b1, const float* __restrict__ b2,
                const float* __restrict__ b3, const float* __restrict__ W4,
                const float* __restrict__ b4,
                const __bf16* __restrict__ Wh, const __bf16* __restrict__ Wl,
                int n_eq_blocks,
                float* __restrict__ out, float* __restrict__ out_b)
{
    __shared__ __align__(16) __bf16 Hh[3 * MPTS][LDP];
    __shared__ __align__(16) __bf16 Hl[3 * MPTS][LDP];

    const int tid  = threadIdx.x;
    const int lane = tid & 63;
    const int wv   = tid >> 6;

    if (blockIdx.x >= (unsigned)n_eq_blocks) {
        // ============ boundary path: plain fp32 forward, 16 pts ============
        float (*HV)[HID] = (float(*)[HID])&Hh[0][0];   // 16KB < 25KB of Hh
        const int rbase = wv * 4;
        const int pbase = (blockIdx.x - n_eq_blocks) * 16 + rbase;

        #pragma unroll
        for (int c = 0; c < 4; ++c) {
            const int   j  = lane + 64 * c;
            const float w  = W0[j];
            const float bb = b0[j];
            #pragma unroll
            for (int p = 0; p < 4; ++p)
                HV[rbase + p][j] = fast_tanh(xb[pbase + p] * w + bb);
        }
        __syncthreads();

        const float* Ws[3] = {W1f, W2f, W3f};
        const float* bs[3] = {b1, b2, b3};

        #pragma unroll
        for (int l = 0; l < 3; ++l) {
            const float* __restrict__ W = Ws[l];
            const float* __restrict__ b = bs[l];

            float zv[4][4];
            #pragma unroll
            for (int p = 0; p < 4; ++p)
                #pragma unroll
                for (int c = 0; c < 4; ++c)
                    zv[p][c] = b[lane + 64 * c];

            for (int i = 0; i < HID; i += 4) {
                float w[4][4];
                #pragma unroll
                for (int qq = 0; qq < 4; ++qq)
                    #pragma unroll
                    for (int c = 0; c < 4; ++c)
                        w[qq][c] = W[(i + qq) * HID + lane + 64 * c];

                #pragma unroll
                for (int p = 0; p < 4; ++p) {
                    const float4 av = *(const float4*)&HV[rbase + p][i];
                    #pragma unroll
                    for (int qq = 0; qq < 4; ++qq) {
                        const float a_v = ((const float*)&av)[qq];
                        #pragma unroll
                        for (int c = 0; c < 4; ++c)
                            zv[p][c] = fmaf(a_v, w[qq][c], zv[p][c]);
                    }
                }
            }
            __syncthreads();

            #pragma unroll
            for (int p = 0; p < 4; ++p)
                #pragma unroll
                for (int c = 0; c < 4; ++c)
                    HV[rbase + p][lane + 64 * c] = fast_tanh(zv[p][c]);
            __syncthreads();
        }

        const float bias4 = b4[0];
        #pragma unroll
        for (int p = 0; p < 4; ++p) {
            float acc = 0.0f;
            #pragma unroll
            for (int c = 0; c < 4; ++c) {
                const int j = lane + 64 * c;
                acc = fmaf(HV[rbase + p][j], W4[j], acc);
            }
            #pragma unroll
            for (int off = 32; off > 0; off >>= 1)
                acc += __shfl_down(acc, off, 64);
            if (lane == 0) out_b[pbase + p] = acc + bias4;
        }
        return;
    }

    // ==================== equation path: jet + MFMA ====================
    const int m  = lane & 15;     // A-frag row / C col
    const int q  = lane >> 4;     // quad
    const int pb = blockIdx.x * MPTS;

    bf16x8 AH[3], AL[3], BH[4], BL[4];
    f32x4  accv[4], accd[4], accs[4];

    // static per-lane byte offset of nt=0 B-frag within a ks-slab
    const int bofs = wv * 4 * 4096 + lane * 8;     // elements

    // ---- layer 0: col c = tid, all 16 points ----
    {
        const int   c  = tid;
        const float w  = W0[c];
        const float bb = b0[c];
        #pragma unroll
        for (int p = 0; p < MPTS; ++p) {
            const float xv = x[pb + p];
            const float v  = fast_tanh(xv * w + bb);
            const float s2 = 1.0f - v * v;
            const float d  = s2 * w;
            const float s  = -2.0f * v * s2 * w * w;
            const __bf16 vh = (__bf16)v;  const __bf16 vl = (__bf16)(v - (float)vh);
            const __bf16 dh = (__bf16)d;  const __bf16 dl = (__bf16)(d - (float)dh);
            const __bf16 sh = (__bf16)s;  const __bf16 sl = (__bf16)(s - (float)sh);
            Hh[p][c]            = vh;  Hl[p][c]            = vl;
            Hh[MPTS + p][c]     = dh;  Hl[MPTS + p][c]     = dl;
            Hh[2 * MPTS + p][c] = sh;  Hl[2 * MPTS + p][c] = sl;
        }
    }
    __syncthreads();

    const float* bias[3] = {b1, b2, b3};

    for (int l = 0; l < 3; ++l) {
        const __bf16* __restrict__ whB = Wh + l * HID * HID;
        const __bf16* __restrict__ wlB = Wl + l * HID * HID;

        #pragma unroll
        for (int nt = 0; nt < 4; ++nt) {
            accv[nt] = (f32x4)0.0f;
            accd[nt] = (f32x4)0.0f;
            accs[nt] = (f32x4)0.0f;
        }

        #pragma unroll 1
        for (int ks = 0; ks < 8; ++ks) {
            // B: global, fragment-order; uniform ks advance (SGPR-friendly)
            const __bf16* __restrict__ wh = whB + ks * 512;
            const __bf16* __restrict__ wl = wlB + ks * 512;
            #pragma unroll
            for (int nt = 0; nt < 4; ++nt) {
                BH[nt] = *(const bf16x8*)(wh + bofs + nt * 4096);
                BL[nt] = *(const bf16x8*)(wl + bofs + nt * 4096);
            }
            // A: LDS
            const int kk = ks * 32 + q * 8;
            #pragma unroll
            for (int mt = 0; mt < 3; ++mt) {
                AH[mt] = *(const bf16x8*)&Hh[mt * MPTS + m][kk];
                AL[mt] = *(const bf16x8*)&Hl[mt * MPTS + m][kk];
            }
            // 36-MFMA burst, term-major (same-acc dep spacing 12)
            #pragma unroll
            for (int nt = 0; nt < 4; ++nt) {
                accv[nt] = __builtin_amdgcn_mfma_f32_16x16x32_bf16(AH[0], BH[nt], accv[nt], 0, 0, 0);
                accd[nt] = __builtin_amdgcn_mfma_f32_16x16x32_bf16(AH[1], BH[nt], accd[nt], 0, 0, 0);
                accs[nt] = __builtin_amdgcn_mfma_f32_16x16x32_bf16(AH[2], BH[nt], accs[nt], 0, 0, 0);
            }
            #pragma unroll
            for (int nt = 0; nt < 4; ++nt) {
                accv[nt] = __builtin_amdgcn_mfma_f32_16x16x32_bf16(AH[0], BL[nt], accv[nt], 0, 0, 0);
                accd[nt] = __builtin_amdgcn_mfma_f32_16x16x32_bf16(AH[1], BL[nt], accd[nt], 0, 0, 0);
                accs[nt] = __builtin_amdgcn_mfma_f32_16x16x32_bf16(AH[2], BL[nt], accs[nt], 0, 0, 0);
            }
            #pragma unroll
            for (int nt = 0; nt < 4; ++nt) {
                accv[nt] = __builtin_amdgcn_mfma_f32_16x16x32_bf16(AL[0], BH[nt], accv[nt], 0, 0, 0);
                accd[nt] = __builtin_amdgcn_mfma_f32_16x16x32_bf16(AL[1], BH[nt], accd[nt], 0, 0, 0);
                accs[nt] = __builtin_amdgcn_mfma_f32_16x16x32_bf16(AL[2], BH[nt], accs[nt], 0, 0, 0);
            }
        }

        __syncthreads();   // all waves done READING H for this layer

        // ---- fused jet epilogue: compute from acc and write H directly ----
        const float* __restrict__ bvec = bias[l];
        #pragma unroll
        for (int nt = 0; nt < 4; ++nt) {
            const int col = (wv * 4 + nt) * 16 + m;
            const float bb = bvec[col];
            #pragma unroll
            for (int r = 0; r < 4; ++r) {
                const int pt = q * 4 + r;
                const float zd = accd[nt][r];
                const float zs = accs[nt][r];
                const float v  = fast_tanh(accv[nt][r] + bb);
                const float s2 = 1.0f - v * v;
                const float d  = s2 * zd;
                const float s  = s2 * zs - 2.0f * v * s2 * zd * zd;
                const __bf16 vh = (__bf16)v;  const __bf16 vl = (__bf16)(v - (float)vh);
                const __bf16 dh = (__bf16)d;  const __bf16 dl = (__bf16)(d - (float)dh);
                const __bf16 sh = (__bf16)s;  const __bf16 sl = (__bf16)(s - (float)sh);
                Hh[pt][col]            = vh;  Hl[pt][col]            = vl;
                Hh[MPTS + pt][col]     = dh;  Hl[MPTS + pt][col]     = dl;
                Hh[2 * MPTS + pt][col] = sh;  Hl[2 * MPTS + pt][col] = sl;
            }
        }
        __syncthreads();   // writes visible before next layer / final dot
    }

    // ---- final: d2u[pt] = sum_j h''[pt][j] * W4[j] ----
    {
        const int pt = tid >> 4;
        const int cc = tid & 15;
        float acc = 0.0f;
        #pragma unroll
        for (int j = 0; j < 16; ++j) {
            const int col = cc * 16 + j;
            const float hv = (float)Hh[2 * MPTS + pt][col] + (float)Hl[2 * MPTS + pt][col];
            acc = fmaf(hv, W4[col], acc);
        }
        #pragma unroll
        for (int off = 8; off > 0; off >>= 1)
            acc += __shfl_down(acc, off, 64);
        if (cc == 0) out[pb + pt] = acc;
    }
}

extern "C" void kernel_launch(void* const* d_in, const int* in_sizes, int n_in,
                              void* d_out, int out_size, void* d_ws, size_t ws_size,
                              hipStream_t stream) {
    const float* xe = (const float*)d_in[0];
    const float* xb = (const float*)d_in[1];
    const float* W0 = (const float*)d_in[2];
    const float* b0 = (const float*)d_in[3];
    const float* W1 = (const float*)d_in[4];
    const float* b1 = (const float*)d_in[5];
    const float* W2 = (const float*)d_in[6];
    const float* b2 = (const float*)d_in[7];
    const float* W3 = (const float*)d_in[8];
    const float* b3 = (const float*)d_in[9];
    const float* W4 = (const float*)d_in[10];
    const float* b4 = (const float*)d_in[11];
    float* out = (float*)d_out;

    const int n_eq = in_sizes[0];   // 262144
    const int n_b  = in_sizes[1];   // 8192

    __bf16* Wh = (__bf16*)d_ws;                    // 3*256*256 bf16 = 384 KB
    __bf16* Wl = Wh + WELEM;                       // another 384 KB

    prep_w<<<WELEM / 256, 256, 0, stream>>>(W1, W2, W3, Wh, Wl);

    const int nbe = n_eq / MPTS;       // 16384 eq blocks
    const int nbb = n_b / 16;          // 512 bnd blocks
    pinn_fused<<<nbe + nbb, 256, 0, stream>>>(
        xe, xb, W0, b0, W1, W2, W3, b1, b2, b3, W4, b4,
        Wh, Wl, nbe, out, out + n_eq);
}